// Round 8
// baseline (509.536 us; speedup 1.0000x reference)
//
#include <hip/hip_runtime.h>

#define N_NODES 32768
#define N_EDGES 524288
#define CHUNK_STRIDE ((size_t)N_NODES * 32)   // shorts per feature-chunk table

typedef __attribute__((ext_vector_type(8))) short short8;
typedef __attribute__((ext_vector_type(4))) float floatx4;

#define GLOBAL_AS __attribute__((address_space(1)))
#define LDS_AS __attribute__((address_space(3)))

__device__ __forceinline__ unsigned short f2bf(float x) {
    union { float f; unsigned u; } v; v.f = x;
    unsigned r = v.u + 0x7FFF + ((v.u >> 16) & 1);
    return (unsigned short)(r >> 16);
}
__device__ __forceinline__ float bf2f(unsigned short u) {
    union { unsigned u; float f; } v; v.u = ((unsigned)u) << 16;
    return v.f;
}

// ================================================================ graph preprocessing
// Atomic-free CSR build (round 7): LDS byte histograms -> dense -> prefix -> place.

__global__ __launch_bounds__(256) void k_hist(const int* __restrict__ src,
                                              const int* __restrict__ dst,
                                              unsigned int* __restrict__ histOut32,
                                              unsigned int* __restrict__ histIn32) {
    __shared__ unsigned int hOut[8192];
    __shared__ unsigned int hIn[8192];
    int t = threadIdx.x, b = blockIdx.x;
    for (int i = t; i < 8192; i += 256) { hOut[i] = 0; hIn[i] = 0; }
    __syncthreads();
    int base = b * 4096;
    for (int i = t; i < 4096; i += 256) {
        int s = src[base + i], d = dst[base + i];
        atomicAdd(&hOut[s >> 2], 1u << ((s & 3) * 8));
        atomicAdd(&hIn[d >> 2], 1u << ((d & 3) * 8));
    }
    __syncthreads();
    for (int i = t; i < 8192; i += 256) {
        histOut32[b * 8192 + i] = hOut[i];
        histIn32[b * 8192 + i] = hIn[i];
    }
}

__global__ __launch_bounds__(256) void k_merge(const unsigned int* __restrict__ histOut32,
                                               const unsigned int* __restrict__ histIn32,
                                               unsigned int* __restrict__ pre32,
                                               int* __restrict__ in_deg,
                                               float* __restrict__ ns,
                                               float* __restrict__ nd) {
    int g = blockIdx.x * 256 + threadIdx.x;
    int ri0 = 0, ri1 = 0, ri2 = 0, ri3 = 0;
    for (int b = 0; b < 128; b++) {
        pre32[b * 8192 + g] = (unsigned)ri0 | ((unsigned)ri1 << 8) |
                              ((unsigned)ri2 << 16) | ((unsigned)ri3 << 24);
        unsigned int v = histIn32[b * 8192 + g];
        ri0 += v & 255; ri1 += (v >> 8) & 255; ri2 += (v >> 16) & 255; ri3 += (v >> 24) & 255;
    }
    in_deg[g * 4 + 0] = ri0; in_deg[g * 4 + 1] = ri1;
    in_deg[g * 4 + 2] = ri2; in_deg[g * 4 + 3] = ri3;
    nd[g * 4 + 0] = ri0 > 0 ? rsqrtf((float)ri0) : 1.0f;
    nd[g * 4 + 1] = ri1 > 0 ? rsqrtf((float)ri1) : 1.0f;
    nd[g * 4 + 2] = ri2 > 0 ? rsqrtf((float)ri2) : 1.0f;
    nd[g * 4 + 3] = ri3 > 0 ? rsqrtf((float)ri3) : 1.0f;
    int ro0 = 0, ro1 = 0, ro2 = 0, ro3 = 0;
    for (int b = 0; b < 128; b++) {
        unsigned int v = histOut32[b * 8192 + g];
        ro0 += v & 255; ro1 += (v >> 8) & 255; ro2 += (v >> 16) & 255; ro3 += (v >> 24) & 255;
    }
    ns[g * 4 + 0] = ro0 > 0 ? rsqrtf((float)ro0) : 1.0f;
    ns[g * 4 + 1] = ro1 > 0 ? rsqrtf((float)ro1) : 1.0f;
    ns[g * 4 + 2] = ro2 > 0 ? rsqrtf((float)ro2) : 1.0f;
    ns[g * 4 + 3] = ro3 > 0 ? rsqrtf((float)ro3) : 1.0f;
}

__global__ void k_scan(const int* __restrict__ in_deg, int* __restrict__ row_ptr) {
    __shared__ int part[1024];
    int t = threadIdx.x;
    int base = t * 32;
    int local[32];
    int s = 0;
    for (int i = 0; i < 32; i++) { local[i] = s; s += in_deg[base + i]; }
    part[t] = s;
    __syncthreads();
    for (int off = 1; off < 1024; off <<= 1) {
        int v = (t >= off) ? part[t - off] : 0;
        __syncthreads();
        part[t] += v;
        __syncthreads();
    }
    int prev = (t == 0) ? 0 : part[t - 1];
    for (int i = 0; i < 32; i++) row_ptr[base + i] = prev + local[i];
    if (t == 1023) row_ptr[N_NODES] = part[1023];
}

__global__ __launch_bounds__(256) void k_place(const int* __restrict__ src,
                                               const int* __restrict__ dst,
                                               const unsigned int* __restrict__ pre32,
                                               const int* __restrict__ row_ptr,
                                               int* __restrict__ csr_src) {
    __shared__ unsigned int cur[8192];
    int t = threadIdx.x, b = blockIdx.x;
    for (int i = t; i < 8192; i += 256) cur[i] = 0;
    __syncthreads();
    int base = b * 4096;
    const unsigned int* preb = pre32 + b * 8192;
    for (int i = t; i < 4096; i += 256) {
        int s = src[base + i], d = dst[base + i];
        int sh = (d & 3) * 8;
        unsigned int old = atomicAdd(&cur[d >> 2], 1u << sh);
        int rank = (old >> sh) & 255;
        int pb = (preb[d >> 2] >> sh) & 255;
        csr_src[row_ptr[d] + pb + rank] = s;
    }
}

// ---------------------------------------------- all 6 weight transposes in ONE kernel
struct TransDescs {
    const float* W[6];
    unsigned short* Wt[6];
    int K[6], N[6];
    int end[6];
};

__global__ __launch_bounds__(256) void k_transpose_all(TransDescs d) {
    int id = blockIdx.x, s = 0;
#pragma unroll
    for (int i = 0; i < 6; i++) if (id >= d.end[i]) s = i + 1;
    int base = (s == 0) ? 0 : d.end[s - 1];
    int t = id - base;
    int K = d.K[s], N = d.N[s];
    int ncols = N >> 5;
    int n0 = (t % ncols) * 32, k0 = (t / ncols) * 32;
    const float* W = d.W[s];
    unsigned short* Wt = d.Wt[s];
    __shared__ float tile[32][33];
    int tx = threadIdx.x & 31, ty = threadIdx.x >> 5;
    for (int r = 0; r < 32; r += 8)
        tile[ty + r][tx] = W[(size_t)(k0 + ty + r) * N + n0 + tx];
    __syncthreads();
    for (int r = 0; r < 32; r += 8)
        Wt[(size_t)(n0 + ty + r) * K + k0 + tx] = f2bf(tile[tx][ty + r]);
}

// ---------------------------------------------- x * ns[node] -> CHUNK-MAJOR bf16 table
// layout: [chunk=f>>5][node][f&31]; each 2 MB chunk is one XCD's gather slice.
__global__ __launch_bounds__(256) void k_scale_x(const float* __restrict__ x,
                                                 const float* __restrict__ ns,
                                                 unsigned short* __restrict__ xsb) {
    int i = blockIdx.x * 256 + threadIdx.x;  // float4 index
    float4 v = ((const float4*)x)[i];
    int n = i >> 6;
    int f0 = (i & 63) * 4;
    float sc = ns[n];
    ushort4 o;
    o.x = f2bf(v.x * sc); o.y = f2bf(v.y * sc);
    o.z = f2bf(v.z * sc); o.w = f2bf(v.w * sc);
    *(ushort4*)(xsb + (size_t)(f0 >> 5) * CHUNK_STRIDE + (size_t)n * 32 + (f0 & 31)) = o;
}

// ------------------------------------------------ XCD-sliced aggregation
// Grid (8, N_NODES/8): blockIdx.x = feature chunk -> XCD via linear-ID %8 round-robin.
// Each XCD's gather working set = its 2 MB chunk slice -> L2-resident.
// Half-wave = one node: el = hl>>2 (8 parallel edges), fl = hl&3 (4x16B feature sublanes).
__global__ __launch_bounds__(256) void k_aggregate(
        const unsigned short* __restrict__ hs,   // chunk-major [8][N_NODES][32]
        const int* __restrict__ row_ptr,
        const int* __restrict__ csr_src, const float* __restrict__ nd,
        unsigned short* __restrict__ aggb) {     // row-major [N_NODES][256]
    const int c = blockIdx.x;
    const int g = blockIdx.y;
    const int wave = threadIdx.x >> 6, lane = threadIdx.x & 63;
    const int half = lane >> 5, hl = lane & 31;
    const int el = hl >> 2, fl = hl & 3;
    const int n = (g * 4 + wave) * 2 + half;
    const int beg = row_ptr[n], end = row_ptr[n + 1];
    const unsigned short* hc = hs + (size_t)c * CHUNK_STRIDE + fl * 8;
    float acc[8];
#pragma unroll
    for (int k = 0; k < 8; k++) acc[k] = 0.f;
    int e = beg;
    for (; e + 16 <= end; e += 16) {
        int s0 = csr_src[e + el];
        int s1 = csr_src[e + 8 + el];
        short8 v0 = *(const short8*)(hc + (size_t)s0 * 32);
        short8 v1 = *(const short8*)(hc + (size_t)s1 * 32);
#pragma unroll
        for (int k = 0; k < 8; k++)
            acc[k] += bf2f((unsigned short)v0[k]) + bf2f((unsigned short)v1[k]);
    }
    if (e + 8 <= end) {
        int s = csr_src[e + el];
        short8 v = *(const short8*)(hc + (size_t)s * 32);
#pragma unroll
        for (int k = 0; k < 8; k++) acc[k] += bf2f((unsigned short)v[k]);
        e += 8;
    }
    if (e + el < end) {
        int s = csr_src[e + el];
        short8 v = *(const short8*)(hc + (size_t)s * 32);
#pragma unroll
        for (int k = 0; k < 8; k++) acc[k] += bf2f((unsigned short)v[k]);
    }
    // reduce the el dimension (stride 4 lanes within each 32-lane half)
#pragma unroll
    for (int off = 16; off >= 4; off >>= 1)
#pragma unroll
        for (int k = 0; k < 8; k++) acc[k] += __shfl_down(acc[k], off);
    if (el == 0) {
        float sc = nd[n];
        short8 o;
#pragma unroll
        for (int k = 0; k < 8; k++) o[k] = (short)f2bf(acc[k] * sc);
        *(short8*)(aggb + (size_t)n * 256 + c * 32 + fl * 8) = o;
    }
}

// ------------------------------------------------ fused 256-wide GEMM + leaky + LN + *ns
// -> CHUNK-MAJOR bf16 table (next layer's gather input)
__global__ __launch_bounds__(256, 2) void gemm_ln(
        const unsigned short* __restrict__ A, const unsigned short* __restrict__ Bt,
        const float* __restrict__ bias, const float* __restrict__ ns,
        unsigned short* __restrict__ hsb) {
    __shared__ __align__(16) unsigned short As[2][128 * 32];
    __shared__ __align__(16) unsigned short Bs[2][256 * 32];
    __shared__ float sSum[2][128], sSum2[2][128], sMa[128], sMb[128];
    const int tid = threadIdx.x;
    const int lane = tid & 63;
    const int w = tid >> 6;
    const int wr = (w >> 1) * 64;
    const int wc = (w & 1) * 128;
    const int rowBase = blockIdx.x * 128;
    const int K = 256;

    floatx4 acc[4][8];
#pragma unroll
    for (int i = 0; i < 4; i++)
#pragma unroll
        for (int j = 0; j < 8; j++) acc[i][j] = (floatx4){0.f, 0.f, 0.f, 0.f};

    const int pr = lane >> 3;
    const int uu = (lane & 7) ^ pr;
    const int rowInGrp = pr * 2 + (uu >> 2);
    const int kc = (uu & 3) * 8;
    const unsigned short* gA = A + (size_t)(rowBase + w * 32 + rowInGrp) * K + kc;
    const unsigned short* gB = Bt + (size_t)(w * 64 + rowInGrp) * K + kc;
    const int aBase = (w * 32) * 32;
    const int bBase = (w * 64) * 32;

    const int q = lane >> 4;
    const int ln = lane & 15;
    const int uf = (((ln & 1) << 2) | q) ^ ((ln >> 1) & 7);

#define STAGE(buf_, koff_)                                                               \
    {                                                                                    \
        unsigned short* lA = As[buf_] + aBase;                                           \
        unsigned short* lB = Bs[buf_] + bBase;                                           \
        __builtin_amdgcn_global_load_lds((const GLOBAL_AS short*)(gA + (koff_)),         \
                                         (LDS_AS short*)lA, 16, 0, 0);                   \
        __builtin_amdgcn_global_load_lds((const GLOBAL_AS short*)(gA + (koff_) + (size_t)16 * K), \
                                         (LDS_AS short*)(lA + 16 * 32), 16, 0, 0);       \
        __builtin_amdgcn_global_load_lds((const GLOBAL_AS short*)(gB + (koff_)),         \
                                         (LDS_AS short*)lB, 16, 0, 0);                   \
        __builtin_amdgcn_global_load_lds((const GLOBAL_AS short*)(gB + (koff_) + (size_t)16 * K), \
                                         (LDS_AS short*)(lB + 16 * 32), 16, 0, 0);       \
        __builtin_amdgcn_global_load_lds((const GLOBAL_AS short*)(gB + (koff_) + (size_t)32 * K), \
                                         (LDS_AS short*)(lB + 32 * 32), 16, 0, 0);       \
        __builtin_amdgcn_global_load_lds((const GLOBAL_AS short*)(gB + (koff_) + (size_t)48 * K), \
                                         (LDS_AS short*)(lB + 48 * 32), 16, 0, 0);       \
    }

    STAGE(0, 0)
    int buf = 0;
    for (int k0 = 0; k0 < K; k0 += 32) {
        __syncthreads();
        if (k0 + 32 < K) STAGE(buf ^ 1, k0 + 32)
        const unsigned short* rA = As[buf];
        const unsigned short* rB = Bs[buf];
        short8 af[4], bfr[8];
#pragma unroll
        for (int i = 0; i < 4; i++)
            af[i] = *(const short8*)(rA + (((wr + i * 16 + ln) >> 1) << 6) + uf * 8);
#pragma unroll
        for (int j = 0; j < 8; j++)
            bfr[j] = *(const short8*)(rB + (((wc + j * 16 + ln) >> 1) << 6) + uf * 8);
#pragma unroll
        for (int i = 0; i < 4; i++)
#pragma unroll
            for (int j = 0; j < 8; j++)
                acc[i][j] = __builtin_amdgcn_mfma_f32_16x16x32_bf16(af[i], bfr[j], acc[i][j], 0, 0, 0);
        buf ^= 1;
    }
#undef STAGE

    float bcol[8];
#pragma unroll
    for (int j = 0; j < 8; j++) bcol[j] = bias[wc + j * 16 + ln];
    const int wcIdx = w & 1;
#pragma unroll
    for (int i = 0; i < 4; i++) {
#pragma unroll
        for (int r = 0; r < 4; r++) {
            float s = 0.f, s2 = 0.f;
#pragma unroll
            for (int j = 0; j < 8; j++) {
                float v = acc[i][j][r] + bcol[j];
                v = v >= 0.f ? v : 0.01f * v;
                s += v; s2 += v * v;
            }
#pragma unroll
            for (int off = 8; off > 0; off >>= 1) {
                s += __shfl_down(s, off, 16);
                s2 += __shfl_down(s2, off, 16);
            }
            if (ln == 0) {
                int row = wr + i * 16 + q * 4 + r;
                sSum[wcIdx][row] = s;
                sSum2[wcIdx][row] = s2;
            }
        }
    }
    __syncthreads();
    if (tid < 128) {
        float mu = (sSum[0][tid] + sSum[1][tid]) * (1.0f / 256.0f);
        float var = (sSum2[0][tid] + sSum2[1][tid]) * (1.0f / 256.0f) - mu * mu;
        float rs = rsqrtf(var + 1e-5f);
        float nsv = ns[rowBase + tid];
        sMa[tid] = rs * nsv;
        sMb[tid] = -mu * rs * nsv;
    }
    __syncthreads();
#pragma unroll
    for (int i = 0; i < 4; i++) {
#pragma unroll
        for (int r = 0; r < 4; r++) {
            int row = wr + i * 16 + q * 4 + r;
            float a = sMa[row], bb = sMb[row];
#pragma unroll
            for (int j = 0; j < 8; j++) {
                int f = wc + j * 16 + ln;
                float v = acc[i][j][r] + bcol[j];
                v = v >= 0.f ? v : 0.01f * v;
                hsb[(size_t)(f >> 5) * CHUNK_STRIDE + (size_t)(rowBase + row) * 32 + (f & 31)] =
                    f2bf(v * a + bb);
            }
        }
    }
}

// ------------------------------------------------ bf16 MFMA GEMM (layer 4 + heads)
template <bool LEAKY, bool OUT_BF16, bool SPLIT>
__global__ __launch_bounds__(256) void gemm_mfma(
        const unsigned short* __restrict__ A, const unsigned short* __restrict__ Bt,
        const float* __restrict__ bias, const float* __restrict__ bias2,
        void* __restrict__ Cv, void* __restrict__ C2v,
        int M, int N, int K) {
    __shared__ __align__(16) unsigned short As[2][128 * 32];
    __shared__ __align__(16) unsigned short Bs[2][128 * 32];
    const int tid = threadIdx.x;
    const int lane = tid & 63;
    const int w = tid >> 6;
    const int wr = (w >> 1) * 64;
    const int wc = (w & 1) * 64;
    const int rowBase = blockIdx.x * 128;
    const int colBase = blockIdx.y * 128;

    floatx4 acc[4][4];
#pragma unroll
    for (int i = 0; i < 4; i++)
#pragma unroll
        for (int j = 0; j < 4; j++) acc[i][j] = (floatx4){0.f, 0.f, 0.f, 0.f};

    const int pr = lane >> 3;
    const int uu = (lane & 7) ^ pr;
    const int srow = w * 32 + pr * 2 + (uu >> 2);
    const int kc = (uu & 3) * 8;
    const unsigned short* gA = A + (size_t)(rowBase + srow) * K + kc;
    const unsigned short* gB = Bt + (size_t)(colBase + srow) * K + kc;
    const int wbase = (w * 32) * 32;

    const int q = lane >> 4;
    const int ln = lane & 15;
    const int uf = (((ln & 1) << 2) | q) ^ ((ln >> 1) & 7);

    {
        unsigned short* lA = As[0] + wbase;
        unsigned short* lB = Bs[0] + wbase;
        __builtin_amdgcn_global_load_lds((const GLOBAL_AS short*)(gA),
                                         (LDS_AS short*)lA, 16, 0, 0);
        __builtin_amdgcn_global_load_lds((const GLOBAL_AS short*)(gA + (size_t)16 * K),
                                         (LDS_AS short*)(lA + 16 * 32), 16, 0, 0);
        __builtin_amdgcn_global_load_lds((const GLOBAL_AS short*)(gB),
                                         (LDS_AS short*)lB, 16, 0, 0);
        __builtin_amdgcn_global_load_lds((const GLOBAL_AS short*)(gB + (size_t)16 * K),
                                         (LDS_AS short*)(lB + 16 * 32), 16, 0, 0);
    }

    int buf = 0;
    for (int k0 = 0; k0 < K; k0 += 32) {
        __syncthreads();
        if (k0 + 32 < K) {
            unsigned short* lA = As[buf ^ 1] + wbase;
            unsigned short* lB = Bs[buf ^ 1] + wbase;
            __builtin_amdgcn_global_load_lds((const GLOBAL_AS short*)(gA + k0 + 32),
                                             (LDS_AS short*)lA, 16, 0, 0);
            __builtin_amdgcn_global_load_lds((const GLOBAL_AS short*)(gA + k0 + 32 + (size_t)16 * K),
                                             (LDS_AS short*)(lA + 16 * 32), 16, 0, 0);
            __builtin_amdgcn_global_load_lds((const GLOBAL_AS short*)(gB + k0 + 32),
                                             (LDS_AS short*)lB, 16, 0, 0);
            __builtin_amdgcn_global_load_lds((const GLOBAL_AS short*)(gB + k0 + 32 + (size_t)16 * K),
                                             (LDS_AS short*)(lB + 16 * 32), 16, 0, 0);
        }
        const unsigned short* rA = As[buf];
        const unsigned short* rB = Bs[buf];
        short8 af[4], bfr[4];
#pragma unroll
        for (int i = 0; i < 4; i++)
            af[i] = *(const short8*)(rA + (((wr + i * 16 + ln) >> 1) << 6) + uf * 8);
#pragma unroll
        for (int j = 0; j < 4; j++)
            bfr[j] = *(const short8*)(rB + (((wc + j * 16 + ln) >> 1) << 6) + uf * 8);
#pragma unroll
        for (int i = 0; i < 4; i++)
#pragma unroll
            for (int j = 0; j < 4; j++)
                acc[i][j] = __builtin_amdgcn_mfma_f32_16x16x32_bf16(af[i], bfr[j], acc[i][j], 0, 0, 0);
        buf ^= 1;
    }
    const int NH = N >> 1;
#pragma unroll
    for (int i = 0; i < 4; i++) {
#pragma unroll
        for (int j = 0; j < 4; j++) {
#pragma unroll
            for (int r = 0; r < 4; r++) {
                int row = rowBase + wr + i * 16 + q * 4 + r;
                int col = colBase + wc + j * 16 + ln;
                float b, *Cf; int cw, ccol;
                if (SPLIT) {
                    bool hi = col >= NH;
                    b = hi ? bias2[col - NH] : bias[col];
                    Cf = (float*)(hi ? C2v : Cv);
                    cw = NH; ccol = hi ? col - NH : col;
                } else {
                    b = bias[col];
                    Cf = (float*)Cv;
                    cw = N; ccol = col;
                }
                float v = acc[i][j][r] + b;
                if (LEAKY) v = v >= 0.f ? v : 0.01f * v;
                if (OUT_BF16)
                    ((unsigned short*)Cv)[(size_t)row * cw + ccol] = f2bf(v);
                else
                    Cf[(size_t)row * cw + ccol] = v;
            }
        }
    }
}

// ------------------------------------------------ fused per-node LN(1024) + partial mean-pool
__global__ __launch_bounds__(256) void k_lnpool(const unsigned short* __restrict__ h4,
                                                float* __restrict__ partial) {
    int g = blockIdx.y, p = blockIdx.x, t = threadIdx.x;
    int wave = t >> 6;
    __shared__ float ss[4], ss2[4];
    float4 acc = make_float4(0.f, 0.f, 0.f, 0.f);
    for (int i = 0; i < 32; i++) {
        int node = (g * 8 + p) * 32 + i;
        ushort4 vb = *(const ushort4*)(h4 + (size_t)node * 1024 + t * 4);
        float4 v = make_float4(bf2f(vb.x), bf2f(vb.y), bf2f(vb.z), bf2f(vb.w));
        float s = v.x + v.y + v.z + v.w;
        float s2 = v.x * v.x + v.y * v.y + v.z * v.z + v.w * v.w;
#pragma unroll
        for (int off = 32; off > 0; off >>= 1) {
            s += __shfl_down(s, off);
            s2 += __shfl_down(s2, off);
        }
        if ((t & 63) == 0) { ss[wave] = s; ss2[wave] = s2; }
        __syncthreads();
        if (t == 0) {
            float tt = 0.f, tt2 = 0.f;
            for (int w = 0; w < 4; w++) { tt += ss[w]; tt2 += ss2[w]; }
            float mu = tt / 1024.f;
            float var = tt2 / 1024.f - mu * mu;
            ss[0] = mu;
            ss2[0] = rsqrtf(var + 1e-5f);
        }
        __syncthreads();
        float mu = ss[0], inv = ss2[0];
        acc.x += (v.x - mu) * inv;
        acc.y += (v.y - mu) * inv;
        acc.z += (v.z - mu) * inv;
        acc.w += (v.w - mu) * inv;
        __syncthreads();
    }
    *(float4*)(partial + (size_t)(g * 8 + p) * 1024 + t * 4) = acc;
}

__global__ __launch_bounds__(256) void k_pool_final(const float* __restrict__ partial,
                                                    unsigned short* __restrict__ pooledb) {
    int g = blockIdx.x, t = threadIdx.x;
    int wave = t >> 6;
    float4 a = make_float4(0.f, 0.f, 0.f, 0.f);
    for (int p = 0; p < 8; p++) {
        float4 v = *(const float4*)(partial + (size_t)(g * 8 + p) * 1024 + t * 4);
        a.x += v.x; a.y += v.y; a.z += v.z; a.w += v.w;
    }
    const float invn = 1.0f / 256.0f;
    a.x *= invn; a.y *= invn; a.z *= invn; a.w *= invn;
    float s = a.x + a.y + a.z + a.w;
    float s2 = a.x * a.x + a.y * a.y + a.z * a.z + a.w * a.w;
#pragma unroll
    for (int off = 32; off > 0; off >>= 1) {
        s += __shfl_down(s, off);
        s2 += __shfl_down(s2, off);
    }
    __shared__ float ss[4], ss2[4];
    if ((t & 63) == 0) { ss[wave] = s; ss2[wave] = s2; }
    __syncthreads();
    if (t == 0) {
        float tt = 0.f, tt2 = 0.f;
        for (int w = 0; w < 4; w++) { tt += ss[w]; tt2 += ss2[w]; }
        float mu = tt / 1024.f;
        float var = tt2 / 1024.f - mu * mu;
        ss[0] = mu;
        ss2[0] = rsqrtf(var + 1e-5f);
    }
    __syncthreads();
    float mu = ss[0], inv = ss2[0];
    ushort4 o;
    o.x = f2bf((a.x - mu) * inv); o.y = f2bf((a.y - mu) * inv);
    o.z = f2bf((a.z - mu) * inv); o.w = f2bf((a.w - mu) * inv);
    *(ushort4*)(pooledb + (size_t)g * 1024 + t * 4) = o;
}

// ---------------------------------------------------------------- launch
extern "C" void kernel_launch(void* const* d_in, const int* in_sizes, int n_in,
                              void* d_out, int out_size, void* d_ws, size_t ws_size,
                              hipStream_t stream) {
    const float* x  = (const float*)d_in[0];
    const int*   src = (const int*)d_in[1];
    const int*   dst = (const int*)d_in[2];
    const float* W1 = (const float*)d_in[3];  const float* b1 = (const float*)d_in[4];
    const float* W2 = (const float*)d_in[5];  const float* b2 = (const float*)d_in[6];
    const float* W3 = (const float*)d_in[7];  const float* b3 = (const float*)d_in[8];
    const float* W4 = (const float*)d_in[9];  const float* b4 = (const float*)d_in[10];
    const float* Wm = (const float*)d_in[11]; const float* bm = (const float*)d_in[12];
    const float* Wsd = (const float*)d_in[13]; const float* bsd = (const float*)d_in[14];
    float* out = (float*)d_out;

    char* w = (char*)d_ws;
    unsigned short* aggb = (unsigned short*)w; w += (size_t)N_NODES * 256 * 2;
    unsigned short* hsb  = (unsigned short*)w; w += (size_t)N_NODES * 256 * 2;  // chunk-major
    unsigned short* h4b  = (unsigned short*)w; w += (size_t)N_NODES * 1024 * 2;
    float* partial = (float*)w; w += (size_t)128 * 8 * 1024 * 4;
    unsigned short* pooledb = (unsigned short*)w; w += (size_t)128 * 1024 * 2;
    unsigned short* W1t = (unsigned short*)w; w += (size_t)256 * 256 * 2;
    unsigned short* W2t = (unsigned short*)w; w += (size_t)256 * 256 * 2;
    unsigned short* W3t = (unsigned short*)w; w += (size_t)256 * 256 * 2;
    unsigned short* W4t = (unsigned short*)w; w += (size_t)256 * 1024 * 2;
    unsigned short* Wmt = (unsigned short*)w; w += (size_t)1024 * 1024 * 2;  // Wst must follow
    unsigned short* Wst = (unsigned short*)w; w += (size_t)1024 * 1024 * 2;  // contiguous: cat
    float* ns     = (float*)w; w += (size_t)N_NODES * 4;
    float* nd     = (float*)w; w += (size_t)N_NODES * 4;
    unsigned int* histOut32 = (unsigned int*)w; w += (size_t)128 * 8192 * 4;
    unsigned int* histIn32  = (unsigned int*)w; w += (size_t)128 * 8192 * 4;
    unsigned int* pre32     = (unsigned int*)w; w += (size_t)128 * 8192 * 4;
    int* in_deg   = (int*)w;   w += (size_t)N_NODES * 4;
    int* row_ptr  = (int*)w;   w += (size_t)(N_NODES + 1) * 4;
    int* csr_src  = (int*)w;   w += (size_t)N_EDGES * 4;

    // weights (independent of graph work)
    TransDescs td;
    td.W[0] = W1; td.W[1] = W2; td.W[2] = W3; td.W[3] = W4; td.W[4] = Wm; td.W[5] = Wsd;
    td.Wt[0] = W1t; td.Wt[1] = W2t; td.Wt[2] = W3t; td.Wt[3] = W4t; td.Wt[4] = Wmt; td.Wt[5] = Wst;
    td.K[0] = 256; td.K[1] = 256; td.K[2] = 256; td.K[3] = 256; td.K[4] = 1024; td.K[5] = 1024;
    td.N[0] = 256; td.N[1] = 256; td.N[2] = 256; td.N[3] = 1024; td.N[4] = 1024; td.N[5] = 1024;
    td.end[0] = 64; td.end[1] = 128; td.end[2] = 192; td.end[3] = 448; td.end[4] = 1472; td.end[5] = 2496;
    k_transpose_all<<<2496, 256, 0, stream>>>(td);

    // atomic-free graph preprocessing
    k_hist<<<128, 256, 0, stream>>>(src, dst, histOut32, histIn32);
    k_merge<<<32, 256, 0, stream>>>(histOut32, histIn32, pre32, in_deg, ns, nd);
    k_scan<<<1, 1024, 0, stream>>>(in_deg, row_ptr);
    k_place<<<128, 256, 0, stream>>>(src, dst, pre32, row_ptr, csr_src);

    // layer-1 gather table: x * ns -> chunk-major bf16
    k_scale_x<<<N_NODES * 256 / 1024, 256, 0, stream>>>(x, ns, hsb);

    // layers 1-3: XCD-sliced aggregate -> fused GEMM+leaky+LN+*ns -> chunk-major table
    const unsigned short* Wts[3] = {W1t, W2t, W3t};
    const float* bs3[3] = {b1, b2, b3};
    for (int l = 0; l < 3; l++) {
        k_aggregate<<<dim3(8, N_NODES / 8), 256, 0, stream>>>(hsb, row_ptr, csr_src, nd, aggb);
        gemm_ln<<<N_NODES / 128, 256, 0, stream>>>(aggb, Wts[l], bs3[l], ns, hsb);
    }

    // layer 4 (256 -> 1024), bf16 out; LN fused into pool
    k_aggregate<<<dim3(8, N_NODES / 8), 256, 0, stream>>>(hsb, row_ptr, csr_src, nd, aggb);
    gemm_mfma<true, true, false><<<dim3(N_NODES / 128, 8), 256, 0, stream>>>(
        aggb, W4t, b4, nullptr, h4b, nullptr, N_NODES, 1024, 256);

    // per-node LN + mean pool + final LN -> bf16
    k_lnpool<<<dim3(8, 128), 256, 0, stream>>>(h4b, partial);
    k_pool_final<<<128, 256, 0, stream>>>(partial, pooledb);

    // both heads in one GEMM: Bt = [Wmt ; Wst] (contiguous), N=2048, split outputs
    gemm_mfma<false, false, true><<<dim3(1, 16), 256, 0, stream>>>(
        pooledb, Wmt, bm, bsd, out, out + 128 * 1024, 128, 2048, 1024);
}

// Round 9
// 438.687 us; speedup vs baseline: 1.1615x; 1.1615x over previous
//
#include <hip/hip_runtime.h>

#define N_NODES 32768
#define N_EDGES 524288

typedef __attribute__((ext_vector_type(8))) short short8;
typedef __attribute__((ext_vector_type(4))) float floatx4;

#define GLOBAL_AS __attribute__((address_space(1)))
#define LDS_AS __attribute__((address_space(3)))

__device__ __forceinline__ unsigned short f2bf(float x) {
    union { float f; unsigned u; } v; v.f = x;
    unsigned r = v.u + 0x7FFF + ((v.u >> 16) & 1);
    return (unsigned short)(r >> 16);
}
__device__ __forceinline__ float bf2f(unsigned short u) {
    union { unsigned u; float f; } v; v.u = ((unsigned)u) << 16;
    return v.f;
}

// ================================================================ graph preprocessing
// Atomic-free CSR build (round 7): LDS byte histograms -> dense -> prefix -> place.

__global__ __launch_bounds__(256) void k_hist(const int* __restrict__ src,
                                              const int* __restrict__ dst,
                                              unsigned int* __restrict__ histOut32,
                                              unsigned int* __restrict__ histIn32) {
    __shared__ unsigned int hOut[8192];
    __shared__ unsigned int hIn[8192];
    int t = threadIdx.x, b = blockIdx.x;
    for (int i = t; i < 8192; i += 256) { hOut[i] = 0; hIn[i] = 0; }
    __syncthreads();
    int base = b * 4096;
    for (int i = t; i < 4096; i += 256) {
        int s = src[base + i], d = dst[base + i];
        atomicAdd(&hOut[s >> 2], 1u << ((s & 3) * 8));
        atomicAdd(&hIn[d >> 2], 1u << ((d & 3) * 8));
    }
    __syncthreads();
    for (int i = t; i < 8192; i += 256) {
        histOut32[b * 8192 + i] = hOut[i];
        histIn32[b * 8192 + i] = hIn[i];
    }
}

__global__ __launch_bounds__(256) void k_merge(const unsigned int* __restrict__ histOut32,
                                               const unsigned int* __restrict__ histIn32,
                                               unsigned int* __restrict__ pre32,
                                               int* __restrict__ in_deg,
                                               float* __restrict__ ns,
                                               float* __restrict__ nd) {
    int g = blockIdx.x * 256 + threadIdx.x;
    int ri0 = 0, ri1 = 0, ri2 = 0, ri3 = 0;
    for (int b = 0; b < 128; b++) {
        pre32[b * 8192 + g] = (unsigned)ri0 | ((unsigned)ri1 << 8) |
                              ((unsigned)ri2 << 16) | ((unsigned)ri3 << 24);
        unsigned int v = histIn32[b * 8192 + g];
        ri0 += v & 255; ri1 += (v >> 8) & 255; ri2 += (v >> 16) & 255; ri3 += (v >> 24) & 255;
    }
    in_deg[g * 4 + 0] = ri0; in_deg[g * 4 + 1] = ri1;
    in_deg[g * 4 + 2] = ri2; in_deg[g * 4 + 3] = ri3;
    nd[g * 4 + 0] = ri0 > 0 ? rsqrtf((float)ri0) : 1.0f;
    nd[g * 4 + 1] = ri1 > 0 ? rsqrtf((float)ri1) : 1.0f;
    nd[g * 4 + 2] = ri2 > 0 ? rsqrtf((float)ri2) : 1.0f;
    nd[g * 4 + 3] = ri3 > 0 ? rsqrtf((float)ri3) : 1.0f;
    int ro0 = 0, ro1 = 0, ro2 = 0, ro3 = 0;
    for (int b = 0; b < 128; b++) {
        unsigned int v = histOut32[b * 8192 + g];
        ro0 += v & 255; ro1 += (v >> 8) & 255; ro2 += (v >> 16) & 255; ro3 += (v >> 24) & 255;
    }
    ns[g * 4 + 0] = ro0 > 0 ? rsqrtf((float)ro0) : 1.0f;
    ns[g * 4 + 1] = ro1 > 0 ? rsqrtf((float)ro1) : 1.0f;
    ns[g * 4 + 2] = ro2 > 0 ? rsqrtf((float)ro2) : 1.0f;
    ns[g * 4 + 3] = ro3 > 0 ? rsqrtf((float)ro3) : 1.0f;
}

__global__ void k_scan(const int* __restrict__ in_deg, int* __restrict__ row_ptr) {
    __shared__ int part[1024];
    int t = threadIdx.x;
    int base = t * 32;
    int local[32];
    int s = 0;
    for (int i = 0; i < 32; i++) { local[i] = s; s += in_deg[base + i]; }
    part[t] = s;
    __syncthreads();
    for (int off = 1; off < 1024; off <<= 1) {
        int v = (t >= off) ? part[t - off] : 0;
        __syncthreads();
        part[t] += v;
        __syncthreads();
    }
    int prev = (t == 0) ? 0 : part[t - 1];
    for (int i = 0; i < 32; i++) row_ptr[base + i] = prev + local[i];
    if (t == 1023) row_ptr[N_NODES] = part[1023];
}

__global__ __launch_bounds__(256) void k_place(const int* __restrict__ src,
                                               const int* __restrict__ dst,
                                               const unsigned int* __restrict__ pre32,
                                               const int* __restrict__ row_ptr,
                                               int* __restrict__ csr_src) {
    __shared__ unsigned int cur[8192];
    int t = threadIdx.x, b = blockIdx.x;
    for (int i = t; i < 8192; i += 256) cur[i] = 0;
    __syncthreads();
    int base = b * 4096;
    const unsigned int* preb = pre32 + b * 8192;
    for (int i = t; i < 4096; i += 256) {
        int s = src[base + i], d = dst[base + i];
        int sh = (d & 3) * 8;
        unsigned int old = atomicAdd(&cur[d >> 2], 1u << sh);
        int rank = (old >> sh) & 255;
        int pb = (preb[d >> 2] >> sh) & 255;
        csr_src[row_ptr[d] + pb + rank] = s;
    }
}

// ---------------------------------------------- all 6 weight transposes in ONE kernel
struct TransDescs {
    const float* W[6];
    unsigned short* Wt[6];
    int K[6], N[6];
    int end[6];
};

__global__ __launch_bounds__(256) void k_transpose_all(TransDescs d) {
    int id = blockIdx.x, s = 0;
#pragma unroll
    for (int i = 0; i < 6; i++) if (id >= d.end[i]) s = i + 1;
    int base = (s == 0) ? 0 : d.end[s - 1];
    int t = id - base;
    int K = d.K[s], N = d.N[s];
    int ncols = N >> 5;
    int n0 = (t % ncols) * 32, k0 = (t / ncols) * 32;
    const float* W = d.W[s];
    unsigned short* Wt = d.Wt[s];
    __shared__ float tile[32][33];
    int tx = threadIdx.x & 31, ty = threadIdx.x >> 5;
    for (int r = 0; r < 32; r += 8)
        tile[ty + r][tx] = W[(size_t)(k0 + ty + r) * N + n0 + tx];
    __syncthreads();
    for (int r = 0; r < 32; r += 8)
        Wt[(size_t)(n0 + ty + r) * K + k0 + tx] = f2bf(tile[tx][ty + r]);
}

// ---------------------------------------------- x * ns[node] -> row-major bf16 table
__global__ __launch_bounds__(256) void k_scale_x(const float* __restrict__ x,
                                                 const float* __restrict__ ns,
                                                 unsigned short* __restrict__ xsb) {
    int i = blockIdx.x * 256 + threadIdx.x;  // float4 index
    float4 v = ((const float4*)x)[i];
    float sc = ns[i >> 6];
    ushort4 o;
    o.x = f2bf(v.x * sc); o.y = f2bf(v.y * sc);
    o.z = f2bf(v.z * sc); o.w = f2bf(v.w * sc);
    ((ushort4*)xsb)[i] = o;
}

// ------------------------------------------------ aggregation (gather, CSR by dst)
// Row-major table (round-7 proven form). TWO nodes per wave: half = lane>>5 picks
// the node, hl = lane&31 owns 8 features (16B). 8-edge unroll = 8 loads in flight.
__global__ __launch_bounds__(256) void k_aggregate(
        const unsigned short* __restrict__ hs, const int* __restrict__ row_ptr,
        const int* __restrict__ csr_src, const float* __restrict__ nd,
        unsigned short* __restrict__ aggb) {
    int wave = threadIdx.x >> 6, lane = threadIdx.x & 63;
    int half = lane >> 5, hl = lane & 31;
    int n = (blockIdx.x * 4 + wave) * 2 + half;
    int beg = row_ptr[n], end = row_ptr[n + 1];
    float acc[8];
#pragma unroll
    for (int k = 0; k < 8; k++) acc[k] = 0.f;
    const unsigned short* hp = hs + hl * 8;
    int e = beg;
    for (; e + 8 <= end; e += 8) {
        int s0 = csr_src[e],     s1 = csr_src[e + 1], s2 = csr_src[e + 2], s3 = csr_src[e + 3];
        int s4 = csr_src[e + 4], s5 = csr_src[e + 5], s6 = csr_src[e + 6], s7 = csr_src[e + 7];
        short8 v0 = *(const short8*)(hp + (size_t)s0 * 256);
        short8 v1 = *(const short8*)(hp + (size_t)s1 * 256);
        short8 v2 = *(const short8*)(hp + (size_t)s2 * 256);
        short8 v3 = *(const short8*)(hp + (size_t)s3 * 256);
        short8 v4 = *(const short8*)(hp + (size_t)s4 * 256);
        short8 v5 = *(const short8*)(hp + (size_t)s5 * 256);
        short8 v6 = *(const short8*)(hp + (size_t)s6 * 256);
        short8 v7 = *(const short8*)(hp + (size_t)s7 * 256);
#pragma unroll
        for (int k = 0; k < 8; k++)
            acc[k] += ((bf2f((unsigned short)v0[k]) + bf2f((unsigned short)v1[k])) +
                       (bf2f((unsigned short)v2[k]) + bf2f((unsigned short)v3[k]))) +
                      ((bf2f((unsigned short)v4[k]) + bf2f((unsigned short)v5[k])) +
                       (bf2f((unsigned short)v6[k]) + bf2f((unsigned short)v7[k])));
    }
    for (; e + 2 <= end; e += 2) {
        int s0 = csr_src[e], s1 = csr_src[e + 1];
        short8 v0 = *(const short8*)(hp + (size_t)s0 * 256);
        short8 v1 = *(const short8*)(hp + (size_t)s1 * 256);
#pragma unroll
        for (int k = 0; k < 8; k++)
            acc[k] += bf2f((unsigned short)v0[k]) + bf2f((unsigned short)v1[k]);
    }
    for (; e < end; e++) {
        int s = csr_src[e];
        short8 v = *(const short8*)(hp + (size_t)s * 256);
#pragma unroll
        for (int k = 0; k < 8; k++) acc[k] += bf2f((unsigned short)v[k]);
    }
    float sc = nd[n];
    short8 o;
#pragma unroll
    for (int k = 0; k < 8; k++) o[k] = (short)f2bf(acc[k] * sc);
    *(short8*)(aggb + (size_t)n * 256 + hl * 8) = o;
}

// ------------------------------------------------ fused 256-wide GEMM + leaky + LN + *ns
// -> row-major bf16 table (next layer's gather input)
__global__ __launch_bounds__(256, 2) void gemm_ln(
        const unsigned short* __restrict__ A, const unsigned short* __restrict__ Bt,
        const float* __restrict__ bias, const float* __restrict__ ns,
        unsigned short* __restrict__ hsb) {
    __shared__ __align__(16) unsigned short As[2][128 * 32];
    __shared__ __align__(16) unsigned short Bs[2][256 * 32];
    __shared__ float sSum[2][128], sSum2[2][128], sMa[128], sMb[128];
    const int tid = threadIdx.x;
    const int lane = tid & 63;
    const int w = tid >> 6;
    const int wr = (w >> 1) * 64;
    const int wc = (w & 1) * 128;
    const int rowBase = blockIdx.x * 128;
    const int K = 256;

    floatx4 acc[4][8];
#pragma unroll
    for (int i = 0; i < 4; i++)
#pragma unroll
        for (int j = 0; j < 8; j++) acc[i][j] = (floatx4){0.f, 0.f, 0.f, 0.f};

    const int pr = lane >> 3;
    const int uu = (lane & 7) ^ pr;
    const int rowInGrp = pr * 2 + (uu >> 2);
    const int kc = (uu & 3) * 8;
    const unsigned short* gA = A + (size_t)(rowBase + w * 32 + rowInGrp) * K + kc;
    const unsigned short* gB = Bt + (size_t)(w * 64 + rowInGrp) * K + kc;
    const int aBase = (w * 32) * 32;
    const int bBase = (w * 64) * 32;

    const int q = lane >> 4;
    const int ln = lane & 15;
    const int uf = (((ln & 1) << 2) | q) ^ ((ln >> 1) & 7);

#define STAGE(buf_, koff_)                                                               \
    {                                                                                    \
        unsigned short* lA = As[buf_] + aBase;                                           \
        unsigned short* lB = Bs[buf_] + bBase;                                           \
        __builtin_amdgcn_global_load_lds((const GLOBAL_AS short*)(gA + (koff_)),         \
                                         (LDS_AS short*)lA, 16, 0, 0);                   \
        __builtin_amdgcn_global_load_lds((const GLOBAL_AS short*)(gA + (koff_) + (size_t)16 * K), \
                                         (LDS_AS short*)(lA + 16 * 32), 16, 0, 0);       \
        __builtin_amdgcn_global_load_lds((const GLOBAL_AS short*)(gB + (koff_)),         \
                                         (LDS_AS short*)lB, 16, 0, 0);                   \
        __builtin_amdgcn_global_load_lds((const GLOBAL_AS short*)(gB + (koff_) + (size_t)16 * K), \
                                         (LDS_AS short*)(lB + 16 * 32), 16, 0, 0);       \
        __builtin_amdgcn_global_load_lds((const GLOBAL_AS short*)(gB + (koff_) + (size_t)32 * K), \
                                         (LDS_AS short*)(lB + 32 * 32), 16, 0, 0);       \
        __builtin_amdgcn_global_load_lds((const GLOBAL_AS short*)(gB + (koff_) + (size_t)48 * K), \
                                         (LDS_AS short*)(lB + 48 * 32), 16, 0, 0);       \
    }

    STAGE(0, 0)
    int buf = 0;
    for (int k0 = 0; k0 < K; k0 += 32) {
        __syncthreads();
        if (k0 + 32 < K) STAGE(buf ^ 1, k0 + 32)
        const unsigned short* rA = As[buf];
        const unsigned short* rB = Bs[buf];
        short8 af[4], bfr[8];
#pragma unroll
        for (int i = 0; i < 4; i++)
            af[i] = *(const short8*)(rA + (((wr + i * 16 + ln) >> 1) << 6) + uf * 8);
#pragma unroll
        for (int j = 0; j < 8; j++)
            bfr[j] = *(const short8*)(rB + (((wc + j * 16 + ln) >> 1) << 6) + uf * 8);
#pragma unroll
        for (int i = 0; i < 4; i++)
#pragma unroll
            for (int j = 0; j < 8; j++)
                acc[i][j] = __builtin_amdgcn_mfma_f32_16x16x32_bf16(af[i], bfr[j], acc[i][j], 0, 0, 0);
        buf ^= 1;
    }
#undef STAGE

    float bcol[8];
#pragma unroll
    for (int j = 0; j < 8; j++) bcol[j] = bias[wc + j * 16 + ln];
    const int wcIdx = w & 1;
#pragma unroll
    for (int i = 0; i < 4; i++) {
#pragma unroll
        for (int r = 0; r < 4; r++) {
            float s = 0.f, s2 = 0.f;
#pragma unroll
            for (int j = 0; j < 8; j++) {
                float v = acc[i][j][r] + bcol[j];
                v = v >= 0.f ? v : 0.01f * v;
                s += v; s2 += v * v;
            }
#pragma unroll
            for (int off = 8; off > 0; off >>= 1) {
                s += __shfl_down(s, off, 16);
                s2 += __shfl_down(s2, off, 16);
            }
            if (ln == 0) {
                int row = wr + i * 16 + q * 4 + r;
                sSum[wcIdx][row] = s;
                sSum2[wcIdx][row] = s2;
            }
        }
    }
    __syncthreads();
    if (tid < 128) {
        float mu = (sSum[0][tid] + sSum[1][tid]) * (1.0f / 256.0f);
        float var = (sSum2[0][tid] + sSum2[1][tid]) * (1.0f / 256.0f) - mu * mu;
        float rs = rsqrtf(var + 1e-5f);
        float nsv = ns[rowBase + tid];
        sMa[tid] = rs * nsv;
        sMb[tid] = -mu * rs * nsv;
    }
    __syncthreads();
#pragma unroll
    for (int i = 0; i < 4; i++) {
#pragma unroll
        for (int r = 0; r < 4; r++) {
            int row = wr + i * 16 + q * 4 + r;
            float a = sMa[row], bb = sMb[row];
#pragma unroll
            for (int j = 0; j < 8; j++) {
                float v = acc[i][j][r] + bcol[j];
                v = v >= 0.f ? v : 0.01f * v;
                hsb[(size_t)(rowBase + row) * 256 + wc + j * 16 + ln] = f2bf(v * a + bb);
            }
        }
    }
}

// ------------------------------------------------ bf16 MFMA GEMM (layer 4 + heads)
template <bool LEAKY, bool OUT_BF16, bool SPLIT>
__global__ __launch_bounds__(256) void gemm_mfma(
        const unsigned short* __restrict__ A, const unsigned short* __restrict__ Bt,
        const float* __restrict__ bias, const float* __restrict__ bias2,
        void* __restrict__ Cv, void* __restrict__ C2v,
        int M, int N, int K) {
    __shared__ __align__(16) unsigned short As[2][128 * 32];
    __shared__ __align__(16) unsigned short Bs[2][128 * 32];
    const int tid = threadIdx.x;
    const int lane = tid & 63;
    const int w = tid >> 6;
    const int wr = (w >> 1) * 64;
    const int wc = (w & 1) * 64;
    const int rowBase = blockIdx.x * 128;
    const int colBase = blockIdx.y * 128;

    floatx4 acc[4][4];
#pragma unroll
    for (int i = 0; i < 4; i++)
#pragma unroll
        for (int j = 0; j < 4; j++) acc[i][j] = (floatx4){0.f, 0.f, 0.f, 0.f};

    const int pr = lane >> 3;
    const int uu = (lane & 7) ^ pr;
    const int srow = w * 32 + pr * 2 + (uu >> 2);
    const int kc = (uu & 3) * 8;
    const unsigned short* gA = A + (size_t)(rowBase + srow) * K + kc;
    const unsigned short* gB = Bt + (size_t)(colBase + srow) * K + kc;
    const int wbase = (w * 32) * 32;

    const int q = lane >> 4;
    const int ln = lane & 15;
    const int uf = (((ln & 1) << 2) | q) ^ ((ln >> 1) & 7);

    {
        unsigned short* lA = As[0] + wbase;
        unsigned short* lB = Bs[0] + wbase;
        __builtin_amdgcn_global_load_lds((const GLOBAL_AS short*)(gA),
                                         (LDS_AS short*)lA, 16, 0, 0);
        __builtin_amdgcn_global_load_lds((const GLOBAL_AS short*)(gA + (size_t)16 * K),
                                         (LDS_AS short*)(lA + 16 * 32), 16, 0, 0);
        __builtin_amdgcn_global_load_lds((const GLOBAL_AS short*)(gB),
                                         (LDS_AS short*)lB, 16, 0, 0);
        __builtin_amdgcn_global_load_lds((const GLOBAL_AS short*)(gB + (size_t)16 * K),
                                         (LDS_AS short*)(lB + 16 * 32), 16, 0, 0);
    }

    int buf = 0;
    for (int k0 = 0; k0 < K; k0 += 32) {
        __syncthreads();
        if (k0 + 32 < K) {
            unsigned short* lA = As[buf ^ 1] + wbase;
            unsigned short* lB = Bs[buf ^ 1] + wbase;
            __builtin_amdgcn_global_load_lds((const GLOBAL_AS short*)(gA + k0 + 32),
                                             (LDS_AS short*)lA, 16, 0, 0);
            __builtin_amdgcn_global_load_lds((const GLOBAL_AS short*)(gA + k0 + 32 + (size_t)16 * K),
                                             (LDS_AS short*)(lA + 16 * 32), 16, 0, 0);
            __builtin_amdgcn_global_load_lds((const GLOBAL_AS short*)(gB + k0 + 32),
                                             (LDS_AS short*)lB, 16, 0, 0);
            __builtin_amdgcn_global_load_lds((const GLOBAL_AS short*)(gB + k0 + 32 + (size_t)16 * K),
                                             (LDS_AS short*)(lB + 16 * 32), 16, 0, 0);
        }
        const unsigned short* rA = As[buf];
        const unsigned short* rB = Bs[buf];
        short8 af[4], bfr[4];
#pragma unroll
        for (int i = 0; i < 4; i++)
            af[i] = *(const short8*)(rA + (((wr + i * 16 + ln) >> 1) << 6) + uf * 8);
#pragma unroll
        for (int j = 0; j < 4; j++)
            bfr[j] = *(const short8*)(rB + (((wc + j * 16 + ln) >> 1) << 6) + uf * 8);
#pragma unroll
        for (int i = 0; i < 4; i++)
#pragma unroll
            for (int j = 0; j < 4; j++)
                acc[i][j] = __builtin_amdgcn_mfma_f32_16x16x32_bf16(af[i], bfr[j], acc[i][j], 0, 0, 0);
        buf ^= 1;
    }
    const int NH = N >> 1;
#pragma unroll
    for (int i = 0; i < 4; i++) {
#pragma unroll
        for (int j = 0; j < 4; j++) {
#pragma unroll
            for (int r = 0; r < 4; r++) {
                int row = rowBase + wr + i * 16 + q * 4 + r;
                int col = colBase + wc + j * 16 + ln;
                float b, *Cf; int cw, ccol;
                if (SPLIT) {
                    bool hi = col >= NH;
                    b = hi ? bias2[col - NH] : bias[col];
                    Cf = (float*)(hi ? C2v : Cv);
                    cw = NH; ccol = hi ? col - NH : col;
                } else {
                    b = bias[col];
                    Cf = (float*)Cv;
                    cw = N; ccol = col;
                }
                float v = acc[i][j][r] + b;
                if (LEAKY) v = v >= 0.f ? v : 0.01f * v;
                if (OUT_BF16)
                    ((unsigned short*)Cv)[(size_t)row * cw + ccol] = f2bf(v);
                else
                    Cf[(size_t)row * cw + ccol] = v;
            }
        }
    }
}

// ------------------------------------------------ fused per-node LN(1024) + partial mean-pool
// Barrier-free inner loop: one WAVE per node-row; lane owns 16 of 1024 features.
// Block = 4 waves x 8 nodes = 32 nodes of one graph; single LDS combine at the end.
__global__ __launch_bounds__(256) void k_lnpool(const unsigned short* __restrict__ h4,
                                                float* __restrict__ partial) {
    const int g = blockIdx.y, p = blockIdx.x;
    const int w = threadIdx.x >> 6, lane = threadIdx.x & 63;
    float acc[16];
#pragma unroll
    for (int k = 0; k < 16; k++) acc[k] = 0.f;
    for (int i = 0; i < 8; i++) {
        int node = (g * 8 + p) * 32 + w * 8 + i;
        const unsigned short* row = h4 + (size_t)node * 1024 + lane * 16;
        short8 a = *(const short8*)row;
        short8 b = *(const short8*)(row + 8);
        float v[16];
#pragma unroll
        for (int k = 0; k < 8; k++) v[k] = bf2f((unsigned short)a[k]);
#pragma unroll
        for (int k = 0; k < 8; k++) v[8 + k] = bf2f((unsigned short)b[k]);
        float s = 0.f, s2 = 0.f;
#pragma unroll
        for (int k = 0; k < 16; k++) { s += v[k]; s2 += v[k] * v[k]; }
#pragma unroll
        for (int off = 32; off > 0; off >>= 1) {
            s += __shfl_down(s, off);
            s2 += __shfl_down(s2, off);
        }
        s = __shfl(s, 0);
        s2 = __shfl(s2, 0);
        float mu = s * (1.0f / 1024.0f);
        float var = s2 * (1.0f / 1024.0f) - mu * mu;
        float rs = rsqrtf(var + 1e-5f);
#pragma unroll
        for (int k = 0; k < 16; k++) acc[k] += (v[k] - mu) * rs;
    }
    __shared__ float red[4][1024];
    float* my = red[w] + lane * 16;
#pragma unroll
    for (int k = 0; k < 16; k++) my[k] = acc[k];
    __syncthreads();
    int t = threadIdx.x;
    float4 o = make_float4(0.f, 0.f, 0.f, 0.f);
#pragma unroll
    for (int w2 = 0; w2 < 4; w2++) {
        float4 v = *(const float4*)(red[w2] + t * 4);
        o.x += v.x; o.y += v.y; o.z += v.z; o.w += v.w;
    }
    *(float4*)(partial + (size_t)(g * 8 + p) * 1024 + t * 4) = o;
}

__global__ __launch_bounds__(256) void k_pool_final(const float* __restrict__ partial,
                                                    unsigned short* __restrict__ pooledb) {
    int g = blockIdx.x, t = threadIdx.x;
    int wave = t >> 6;
    float4 a = make_float4(0.f, 0.f, 0.f, 0.f);
    for (int p = 0; p < 8; p++) {
        float4 v = *(const float4*)(partial + (size_t)(g * 8 + p) * 1024 + t * 4);
        a.x += v.x; a.y += v.y; a.z += v.z; a.w += v.w;
    }
    const float invn = 1.0f / 256.0f;
    a.x *= invn; a.y *= invn; a.z *= invn; a.w *= invn;
    float s = a.x + a.y + a.z + a.w;
    float s2 = a.x * a.x + a.y * a.y + a.z * a.z + a.w * a.w;
#pragma unroll
    for (int off = 32; off > 0; off >>= 1) {
        s += __shfl_down(s, off);
        s2 += __shfl_down(s2, off);
    }
    __shared__ float ss[4], ss2[4];
    if ((t & 63) == 0) { ss[wave] = s; ss2[wave] = s2; }
    __syncthreads();
    if (t == 0) {
        float tt = 0.f, tt2 = 0.f;
        for (int w = 0; w < 4; w++) { tt += ss[w]; tt2 += ss2[w]; }
        float mu = tt / 1024.f;
        float var = tt2 / 1024.f - mu * mu;
        ss[0] = mu;
        ss2[0] = rsqrtf(var + 1e-5f);
    }
    __syncthreads();
    float mu = ss[0], inv = ss2[0];
    ushort4 o;
    o.x = f2bf((a.x - mu) * inv); o.y = f2bf((a.y - mu) * inv);
    o.z = f2bf((a.z - mu) * inv); o.w = f2bf((a.w - mu) * inv);
    *(ushort4*)(pooledb + (size_t)g * 1024 + t * 4) = o;
}

// ---------------------------------------------------------------- launch
extern "C" void kernel_launch(void* const* d_in, const int* in_sizes, int n_in,
                              void* d_out, int out_size, void* d_ws, size_t ws_size,
                              hipStream_t stream) {
    const float* x  = (const float*)d_in[0];
    const int*   src = (const int*)d_in[1];
    const int*   dst = (const int*)d_in[2];
    const float* W1 = (const float*)d_in[3];  const float* b1 = (const float*)d_in[4];
    const float* W2 = (const float*)d_in[5];  const float* b2 = (const float*)d_in[6];
    const float* W3 = (const float*)d_in[7];  const float* b3 = (const float*)d_in[8];
    const float* W4 = (const float*)d_in[9];  const float* b4 = (const float*)d_in[10];
    const float* Wm = (const float*)d_in[11]; const float* bm = (const float*)d_in[12];
    const float* Wsd = (const float*)d_in[13]; const float* bsd = (const float*)d_in[14];
    float* out = (float*)d_out;

    char* w = (char*)d_ws;
    unsigned short* aggb = (unsigned short*)w; w += (size_t)N_NODES * 256 * 2;
    unsigned short* hsb  = (unsigned short*)w; w += (size_t)N_NODES * 256 * 2;
    unsigned short* h4b  = (unsigned short*)w; w += (size_t)N_NODES * 1024 * 2;
    float* partial = (float*)w; w += (size_t)128 * 8 * 1024 * 4;
    unsigned short* pooledb = (unsigned short*)w; w += (size_t)128 * 1024 * 2;
    unsigned short* W1t = (unsigned short*)w; w += (size_t)256 * 256 * 2;
    unsigned short* W2t = (unsigned short*)w; w += (size_t)256 * 256 * 2;
    unsigned short* W3t = (unsigned short*)w; w += (size_t)256 * 256 * 2;
    unsigned short* W4t = (unsigned short*)w; w += (size_t)256 * 1024 * 2;
    unsigned short* Wmt = (unsigned short*)w; w += (size_t)1024 * 1024 * 2;  // Wst must follow
    unsigned short* Wst = (unsigned short*)w; w += (size_t)1024 * 1024 * 2;  // contiguous: cat
    float* ns     = (float*)w; w += (size_t)N_NODES * 4;
    float* nd     = (float*)w; w += (size_t)N_NODES * 4;
    unsigned int* histOut32 = (unsigned int*)w; w += (size_t)128 * 8192 * 4;
    unsigned int* histIn32  = (unsigned int*)w; w += (size_t)128 * 8192 * 4;
    unsigned int* pre32     = (unsigned int*)w; w += (size_t)128 * 8192 * 4;
    int* in_deg   = (int*)w;   w += (size_t)N_NODES * 4;
    int* row_ptr  = (int*)w;   w += (size_t)(N_NODES + 1) * 4;
    int* csr_src  = (int*)w;   w += (size_t)N_EDGES * 4;

    // weights (independent of graph work)
    TransDescs td;
    td.W[0] = W1; td.W[1] = W2; td.W[2] = W3; td.W[3] = W4; td.W[4] = Wm; td.W[5] = Wsd;
    td.Wt[0] = W1t; td.Wt[1] = W2t; td.Wt[2] = W3t; td.Wt[3] = W4t; td.Wt[4] = Wmt; td.Wt[5] = Wst;
    td.K[0] = 256; td.K[1] = 256; td.K[2] = 256; td.K[3] = 256; td.K[4] = 1024; td.K[5] = 1024;
    td.N[0] = 256; td.N[1] = 256; td.N[2] = 256; td.N[3] = 1024; td.N[4] = 1024; td.N[5] = 1024;
    td.end[0] = 64; td.end[1] = 128; td.end[2] = 192; td.end[3] = 448; td.end[4] = 1472; td.end[5] = 2496;
    k_transpose_all<<<2496, 256, 0, stream>>>(td);

    // atomic-free graph preprocessing
    k_hist<<<128, 256, 0, stream>>>(src, dst, histOut32, histIn32);
    k_merge<<<32, 256, 0, stream>>>(histOut32, histIn32, pre32, in_deg, ns, nd);
    k_scan<<<1, 1024, 0, stream>>>(in_deg, row_ptr);
    k_place<<<128, 256, 0, stream>>>(src, dst, pre32, row_ptr, csr_src);

    // layer-1 gather table: x * ns -> bf16 (row-major)
    k_scale_x<<<N_NODES * 256 / 1024, 256, 0, stream>>>(x, ns, hsb);

    // layers 1-3: aggregate -> fused GEMM+leaky+LN+*ns -> bf16 table
    const unsigned short* Wts[3] = {W1t, W2t, W3t};
    const float* bs3[3] = {b1, b2, b3};
    for (int l = 0; l < 3; l++) {
        k_aggregate<<<N_NODES / 8, 256, 0, stream>>>(hsb, row_ptr, csr_src, nd, aggb);
        gemm_ln<<<N_NODES / 128, 256, 0, stream>>>(aggb, Wts[l], bs3[l], ns, hsb);
    }

    // layer 4 (256 -> 1024), bf16 out; LN fused into pool
    k_aggregate<<<N_NODES / 8, 256, 0, stream>>>(hsb, row_ptr, csr_src, nd, aggb);
    gemm_mfma<true, true, false><<<dim3(N_NODES / 128, 8), 256, 0, stream>>>(
        aggb, W4t, b4, nullptr, h4b, nullptr, N_NODES, 1024, 256);

    // per-node LN + mean pool + final LN -> bf16
    k_lnpool<<<dim3(8, 128), 256, 0, stream>>>(h4b, partial);
    k_pool_final<<<128, 256, 0, stream>>>(partial, pooledb);

    // both heads in one GEMM: Bt = [Wmt ; Wst] (contiguous), N=2048, split outputs
    gemm_mfma<false, false, true><<<dim3(1, 16), 256, 0, stream>>>(
        pooledb, Wmt, bm, bsd, out, out + 128 * 1024, 128, 2048, 1024);
}